// Round 5
// baseline (310.006 us; speedup 1.0000x reference)
//
#include <hip/hip_runtime.h>
#include <cstdint>

#define DIMC 2048
#define NSEQ 2048
#define BATCH 2
#define NH 16
#define HD 128
#define MROWS 4096            // BATCH*NSEQ
#define NQKV 6144             // 3*DIMC
#define QSCALE 0.08838834764831845f

typedef float f32x4 __attribute__((ext_vector_type(4)));
typedef __bf16 bf16x8 __attribute__((ext_vector_type(8)));
typedef __bf16 bf16x4 __attribute__((ext_vector_type(4)));

__device__ __forceinline__ f32x4 mfma16(bf16x8 a, bf16x8 b, f32x4 c) {
  return __builtin_amdgcn_mfma_f32_16x16x32_bf16(a, b, c, 0, 0, 0);
}

typedef __attribute__((address_space(1))) void gvoid;
typedef __attribute__((address_space(3))) void ldsvoid;

__device__ __forceinline__ void async16(void* lds, const void* g) {
  __builtin_amdgcn_global_load_lds((gvoid*)(uintptr_t)g, (ldsvoid*)(uintptr_t)lds, 16, 0, 0);
}

// raw barrier: no vmcnt drain (unlike __syncthreads); "memory" clobber pins
// LDS loads / stage intrinsics on their side of the barrier.
#define BAR() asm volatile("s_barrier" ::: "memory")
#define VMCNT(n) asm volatile("s_waitcnt vmcnt(" #n ")" ::: "memory")
// partial drain when 12 ds_reads issued in one phase (m201 template)
#define LGKMD() asm volatile("s_waitcnt lgkmcnt(8)" ::: "memory")
// post-barrier drain + pin (rule #18: sched_barrier stops MFMA hoisting)
#define LGKM0() do { asm volatile("s_waitcnt lgkmcnt(0)" ::: "memory"); \
                     __builtin_amdgcn_sched_barrier(0); } while(0)

// ---------------------------------------------------------------------------
// fp32 -> bf16 cast
// ---------------------------------------------------------------------------
__global__ __launch_bounds__(256) void cast_bf16(const float* __restrict__ src,
                                                 __bf16* __restrict__ dst, int n) {
  int i = (blockIdx.x * 256 + threadIdx.x) * 4;
  const int stride = gridDim.x * 1024;
  for (; i < n; i += stride) {
    const float4 v = *(const float4*)(src + i);
    bf16x4 o = {(__bf16)v.x, (__bf16)v.y, (__bf16)v.z, (__bf16)v.w};
    *(bf16x4*)(dst + i) = o;
  }
}

// ---------------------------------------------------------------------------
// QKV GEMM, 256x256 tile, BK=64, 8 waves (2Mx4N), 8-phase pipelined schedule.
// C[M][N] = A[M][K] * B[N][K]^T; K=2048 (32 K-tiles, 16 iterations).
// LDS 128KiB: 2 buffers x { A[2 halves][128][64], B[2 halves][128][64] } bf16.
// 3-bit chunk XOR swizzle within each 128B row (R3, conflicts=0): LDS[row][c]
// holds G[row][c ^ (row&7)]; pre-swizzled global source + same XOR on ds_read.
// R4 restructure (m201-faithful): reads at PHASE TOP (before the barrier) so
// ds_read latency overlaps prev-MFMA drain + barrier wait; buffer validity
// vmcnt moved to end of p3/p7 (before closing barrier). Ledger: outstanding
// at p3/p7 = 14; vmcnt(6) retires exactly the 8 ops of the buffer read next.
// ---------------------------------------------------------------------------
#define RA 0
#define RB 32768
#define BUF1 65536

#define READ_B(Bb) do { \
    bfr[0][0]=ldf(Bb,rB,0);      bfr[0][1]=ldf(Bb,rB,1); \
    bfr[1][0]=ldf(Bb,rB+16,0);   bfr[1][1]=ldf(Bb,rB+16,1); \
    bfr[2][0]=ldf(Bb,rB+32,0);   bfr[2][1]=ldf(Bb,rB+32,1); \
    bfr[3][0]=ldf(Bb,rB+48,0);   bfr[3][1]=ldf(Bb,rB+48,1); } while(0)

#define READ_A(Ab,P) do { \
    afr[0][0]=ldf(Ab,(P*2+0)*16+a,0); afr[0][1]=ldf(Ab,(P*2+0)*16+a,1); \
    afr[1][0]=ldf(Ab,(P*2+1)*16+a,0); afr[1][1]=ldf(Ab,(P*2+1)*16+a,1); } while(0)

#define DO_MFMA(P) do { __builtin_amdgcn_s_setprio(1); \
    _Pragma("unroll") for (int f_=0; f_<2; ++f_) \
    _Pragma("unroll") for (int n_=0; n_<4; ++n_) \
    _Pragma("unroll") for (int k_=0; k_<2; ++k_) \
      acc[P*2+f_][n_] = mfma16(afr[f_][k_], bfr[n_][k_], acc[P*2+f_][n_]); \
    __builtin_amdgcn_s_setprio(0); } while(0)

__global__ __launch_bounds__(512, 2) void qkv256(
    const __bf16* __restrict__ A, const __bf16* __restrict__ Bm,
    __bf16* __restrict__ Qb, __bf16* __restrict__ Kb, __bf16* __restrict__ Vtb,
    const float* __restrict__ bq, const float* __restrict__ bk,
    const float* __restrict__ bv) {
  extern __shared__ __align__(16) char Lds[];
  const int tid = threadIdx.x;
  const int l = tid & 63, w = tid >> 6;
  const int a = l & 15, g = l >> 4;
  const int wm = w >> 2, wn = w & 3;
  const int mbase = blockIdx.y * 256, nbase = blockIdx.x * 256;
  const int wbyte = w * 1024;
  const char* Ag = (const char*)A;
  const char* Bg = (const char*)Bm;
  const int rB = (wn & 1) * 64 + a;

  f32x4 acc[8][4] = {};
  bf16x8 bfr[4][2], afr[2][2];

  // stage one 8KB op: op j = half (j>>1), rows (j&1)*64..+63 of a [2][128][64]
  // bf16 region. LDS dest linear; global source chunk pre-swizzled by row&7.
  auto issue = [&](int bufofs, int regofs, const char* gmat, int grow0, int kt, int j) {
    const int grow = grow0 + (j >> 1) * 128 + (j & 1) * 64 + (tid >> 3);
    const int scol = (((tid & 7) ^ ((tid >> 3) & 7)) * 16);
    async16(Lds + bufofs + regofs + j * 8192 + wbyte,
            gmat + (size_t)grow * (DIMC * 2) + kt * 128 + scol);
  };
  // swizzled fragment read: 16B at (row, k-slice ks); chunk ^= row&7.
  auto ldf = [&](const char* halfbase, int row, int ks) -> bf16x8 {
    const int c = (ks * 64 + g * 16) ^ ((row & 7) << 4);
    return *(const bf16x8*)(halfbase + row * 128 + c);
  };

  // prologue: buf0 <- tile0 (8 ops), buf1 <- tile1 (first 6 ops);
  // vmcnt(6) retires buf0's 8 -> buf0 valid at the barrier.
  issue(0, RB, Bg, nbase, 0, 0); issue(0, RB, Bg, nbase, 0, 1);
  issue(0, RB, Bg, nbase, 0, 2); issue(0, RB, Bg, nbase, 0, 3);
  issue(0, RA, Ag, mbase, 0, 0); issue(0, RA, Ag, mbase, 0, 2);
  issue(0, RA, Ag, mbase, 0, 1); issue(0, RA, Ag, mbase, 0, 3);
  issue(BUF1, RB, Bg, nbase, 1, 0); issue(BUF1, RB, Bg, nbase, 1, 1);
  issue(BUF1, RB, Bg, nbase, 1, 2); issue(BUF1, RB, Bg, nbase, 1, 3);
  issue(BUF1, RA, Ag, mbase, 1, 0); issue(BUF1, RA, Ag, mbase, 1, 2);
  VMCNT(6); BAR();

  const char* A0 = Lds + wm * 16384;
  const char* B0 = Lds + RB + (wn >> 1) * 16384;
  const char* A1 = A0 + BUF1;
  const char* B1 = B0 + BUF1;

  for (int i = 0; i < 16; ++i) {
    const bool more = (i < 15);
    const int t2 = 2 * i + 2, t3 = 2 * i + 3;
    // ---- p0 ---- (buf0 valid since prev p7 vmcnt+bar)
    READ_B(B0); READ_A(A0, 0);
    issue(BUF1, RA, Ag, mbase, 2 * i + 1, 1);
    issue(BUF1, RA, Ag, mbase, 2 * i + 1, 3);
    LGKMD(); BAR(); LGKM0();
    DO_MFMA(0); BAR();
    // ---- p1 ----
    READ_A(A0, 1);
    if (more) { issue(0, RB, Bg, nbase, t2, 0); issue(0, RB, Bg, nbase, t2, 1); }
    BAR(); LGKM0(); DO_MFMA(1); BAR();
    // ---- p2 ----
    READ_A(A0, 2);
    if (more) { issue(0, RB, Bg, nbase, t2, 2); issue(0, RB, Bg, nbase, t2, 3);
                issue(0, RA, Ag, mbase, t2, 0); issue(0, RA, Ag, mbase, t2, 2); }
    BAR(); LGKM0(); DO_MFMA(2); BAR();
    // ---- p3 ---- (vmcnt: retire buf1's 8 ops -> buf1 valid at closing bar)
    READ_A(A0, 3);
    if (more) { VMCNT(6); } else { VMCNT(0); }
    BAR(); LGKM0(); DO_MFMA(3); BAR();
    // ---- p4 ----
    READ_B(B1); READ_A(A1, 0);
    if (more) { issue(0, RA, Ag, mbase, t2, 1); issue(0, RA, Ag, mbase, t2, 3); }
    LGKMD(); BAR(); LGKM0();
    DO_MFMA(0); BAR();
    // ---- p5 ----
    READ_A(A1, 1);
    if (more) { issue(BUF1, RB, Bg, nbase, t3, 0); issue(BUF1, RB, Bg, nbase, t3, 1); }
    BAR(); LGKM0(); DO_MFMA(1); BAR();
    // ---- p6 ----
    READ_A(A1, 2);
    if (more) { issue(BUF1, RB, Bg, nbase, t3, 2); issue(BUF1, RB, Bg, nbase, t3, 3);
                issue(BUF1, RA, Ag, mbase, t3, 0); issue(BUF1, RA, Ag, mbase, t3, 2); }
    BAR(); LGKM0(); DO_MFMA(2); BAR();
    // ---- p7 ---- (vmcnt: retire buf0-t2's 8 ops -> buf0 valid at closing bar)
    READ_A(A1, 3);
    if (more) { VMCNT(6); }
    BAR(); LGKM0(); DO_MFMA(3); BAR();
  }

  // epilogue: bias + scatter Q[B,H,N,D]*scale, K[B,H,N,D], Vt[B,H,D,N]
  const int seg = nbase >> 11;
  const int cin = (nbase & 2047) + wn * 64;
  const float* bias = (seg == 0) ? bq : ((seg == 1) ? bk : bv);
  const float scl = (seg == 0) ? QSCALE : 1.0f;
#pragma unroll
  for (int n = 0; n < 4; ++n) {
    const int c = cin + n * 16 + a;
    const float bb = bias[c];
    const int h = c >> 7, d = c & 127;
#pragma unroll
    for (int m = 0; m < 8; ++m) {
      const int mr = mbase + wm * 128 + m * 16 + g * 4;
      const int b_ = mr >> 11, sq = mr & 2047;
      f32x4 v = acc[m][n];
      if (seg == 2) {
        __bf16* dst = Vtb + ((size_t)(b_ * NH + h) * HD + d) * NSEQ + sq;
        bf16x4 pk = {(__bf16)(v[0] + bb), (__bf16)(v[1] + bb),
                     (__bf16)(v[2] + bb), (__bf16)(v[3] + bb)};
        *(bf16x4*)dst = pk;
      } else {
        __bf16* dst = ((seg == 0) ? Qb : Kb) +
                      ((size_t)(b_ * NH + h) * NSEQ + sq) * HD + d;
#pragma unroll
        for (int j = 0; j < 4; ++j) dst[(size_t)j * HD] = (__bf16)((v[j] + bb) * scl);
      }
    }
  }
}

// ---------------------------------------------------------------------------
// m97-structure 128x128 GEMM for the output projection.
// ---------------------------------------------------------------------------
__global__ __launch_bounds__(256) void gemm_out(
    const __bf16* __restrict__ A, const __bf16* __restrict__ Bm,
    const float* __restrict__ bias0, float* __restrict__ outp) {
  __shared__ __bf16 Al[128 * 32];
  __shared__ __bf16 Bl[128 * 32];
  const int tid = threadIdx.x;
  const int w = tid >> 6, l = tid & 63;
  const int a = l & 15, g = l >> 4;
  const int mbase = blockIdx.y * 128, nbase = blockIdx.x * 128;
  const int wr = w >> 1, wc = w & 1;

  f32x4 acc[4][4] = {};

  const char* Ag = (const char*)A +
      ((size_t)(mbase + w * 32 + (l >> 2)) * DIMC + (size_t)(l & 3) * 8) * 2;
  const char* Bg = (const char*)Bm +
      ((size_t)(nbase + w * 32 + (l >> 2)) * DIMC + (size_t)(l & 3) * 8) * 2;
  char* Alw = (char*)Al + w * 2048;
  char* Blw = (char*)Bl + w * 2048;

  for (int kt = 0; kt < DIMC / 32; ++kt) {
    const size_t ko = (size_t)kt * 64;
    async16(Alw, Ag + ko);
    async16(Alw + 1024, Ag + (size_t)16 * (DIMC * 2) + ko);
    async16(Blw, Bg + ko);
    async16(Blw + 1024, Bg + (size_t)16 * (DIMC * 2) + ko);
    __syncthreads();
    bf16x8 af[4], bf_[4];
#pragma unroll
    for (int m = 0; m < 4; ++m)
      af[m] = *(const bf16x8*)((const char*)Al + (wr * 64 + m * 16 + a) * 64 + g * 16);
#pragma unroll
    for (int n = 0; n < 4; ++n)
      bf_[n] = *(const bf16x8*)((const char*)Bl + (wc * 64 + n * 16 + a) * 64 + g * 16);
#pragma unroll
    for (int m = 0; m < 4; ++m)
#pragma unroll
      for (int n = 0; n < 4; ++n) acc[m][n] = mfma16(af[m], bf_[n], acc[m][n]);
    __syncthreads();
  }

#pragma unroll
  for (int n = 0; n < 4; ++n) {
    const int c = nbase + wc * 64 + n * 16 + a;
    const float bb = bias0[c];
#pragma unroll
    for (int m = 0; m < 4; ++m) {
      const int mr = mbase + wr * 64 + m * 16 + g * 4;
      float* dst = outp + (size_t)mr * DIMC + c;
      f32x4 v = acc[m][n];
#pragma unroll
      for (int j = 0; j < 4; ++j) dst[(size_t)j * DIMC] = v[j] + bb;
    }
  }
}

// ---------------------------------------------------------------------------
// Sliding-window flash attention (unchanged from validated baseline).
// ---------------------------------------------------------------------------
__global__ __launch_bounds__(256) void attn_swa(const __bf16* __restrict__ Qb,
                                                const __bf16* __restrict__ Kb,
                                                const __bf16* __restrict__ Vtb,
                                                __bf16* __restrict__ Ob) {
  __shared__ __bf16 Klds[64 * 128];
  __shared__ __bf16 Vlds[128 * 64];
  __shared__ __bf16 Plds[4 * 16 * 64];
  const int tid = threadIdx.x;
  const int w = tid >> 6, l = tid & 63;
  const int a = l & 15, g = l >> 4;
  const int bh = blockIdx.y;
  const int qbase = blockIdx.x * 64;
  const __bf16* Qg = Qb + (size_t)bh * NSEQ * HD + (size_t)qbase * HD;
  const __bf16* Kg = Kb + (size_t)bh * NSEQ * HD;
  const __bf16* Vg = Vtb + (size_t)bh * HD * NSEQ;

  bf16x8 qf[4];
#pragma unroll
  for (int s = 0; s < 4; ++s)
    qf[s] = *(const bf16x8*)(Qg + (size_t)(w * 16 + a) * HD + s * 32 + g * 8);

  float mrow[4] = {-1e38f, -1e38f, -1e38f, -1e38f};
  float lrow[4] = {0.f, 0.f, 0.f, 0.f};
  f32x4 o[8] = {};

  const int ktlo = (qbase >= 1024) ? ((qbase - 1024) >> 6) : 0;
  const int kthi = qbase >> 6;
  const int qmax = qbase + 63;

  for (int kt = ktlo; kt <= kthi; ++kt) {
    const int kb = kt * 64;
#pragma unroll
    for (int j = 0; j < 4; ++j) {
      const int off = j * 4096 + w * 1024 + l * 16;
      const int row = off >> 8;
      const int cg = ((off >> 4) & 15) ^ (row & 7);
      async16((char*)Klds + j * 4096 + w * 1024,
              (const char*)Kg + (size_t)(kb + row) * 256 + cg * 16);
    }
#pragma unroll
    for (int j = 0; j < 4; ++j) {
      const int off = j * 4096 + w * 1024 + l * 16;
      const int row = off >> 7;
      const int cg = ((off >> 4) & 7) ^ (row & 7);
      async16((char*)Vlds + j * 4096 + w * 1024,
              (const char*)Vg + (size_t)row * (NSEQ * 2) + (size_t)kb * 2 + cg * 16);
    }
    __syncthreads();

    const bool full = (kb >= qmax - 1024) && (kb + 63 <= qbase);
    f32x4 s4[4];
#pragma unroll
    for (int t = 0; t < 4; ++t) {
      f32x4 sc = {};
#pragma unroll
      for (int ds = 0; ds < 4; ++ds) {
        const int row = t * 16 + a;
        const int ch = (ds * 4 + g) ^ (row & 7);
        bf16x8 kf = *(const bf16x8*)((const char*)Klds + row * 256 + ch * 16);
        sc = mfma16(qf[ds], kf, sc);
      }
      s4[t] = sc;
    }
    if (!full) {
#pragma unroll
      for (int t = 0; t < 4; ++t)
#pragma unroll
        for (int i = 0; i < 4; ++i) {
          const int q = qbase + w * 16 + g * 4 + i;
          const int kv = kb + t * 16 + a;
          if (kv > q || kv + 1024 < q) s4[t][i] = -1e30f;
        }
    }
    float pm[4], corr[4], rs[4];
#pragma unroll
    for (int i = 0; i < 4; ++i)
      pm[i] = fmaxf(fmaxf(s4[0][i], s4[1][i]), fmaxf(s4[2][i], s4[3][i]));
#pragma unroll
    for (int i = 0; i < 4; ++i) {
      pm[i] = fmaxf(pm[i], __shfl_xor(pm[i], 1));
      pm[i] = fmaxf(pm[i], __shfl_xor(pm[i], 2));
      pm[i] = fmaxf(pm[i], __shfl_xor(pm[i], 4));
      pm[i] = fmaxf(pm[i], __shfl_xor(pm[i], 8));
      const float nm = fmaxf(mrow[i], pm[i]);
      corr[i] = __expf(mrow[i] - nm);
      mrow[i] = nm;
      rs[i] = 0.f;
    }
#pragma unroll
    for (int t = 0; t < 4; ++t)
#pragma unroll
      for (int i = 0; i < 4; ++i) {
        const float p = __expf(s4[t][i] - mrow[i]);
        s4[t][i] = p;
        rs[i] += p;
      }
#pragma unroll
    for (int i = 0; i < 4; ++i) {
      rs[i] += __shfl_xor(rs[i], 1);
      rs[i] += __shfl_xor(rs[i], 2);
      rs[i] += __shfl_xor(rs[i], 4);
      rs[i] += __shfl_xor(rs[i], 8);
      lrow[i] = lrow[i] * corr[i] + rs[i];
    }
#pragma unroll
    for (int n = 0; n < 8; ++n)
#pragma unroll
      for (int i = 0; i < 4; ++i) o[n][i] *= corr[i];
    char* Pw = (char*)Plds + w * 2048;
#pragma unroll
    for (int t = 0; t < 4; ++t)
#pragma unroll
      for (int i = 0; i < 4; ++i) {
        const int q = g * 4 + i;
        const int byte = (q * 128 + (t * 16 + a) * 2) ^ ((q & 7) << 4);
        *(__bf16*)(Pw + byte) = (__bf16)s4[t][i];
      }
#pragma unroll
    for (int ks = 0; ks < 2; ++ks) {
      const int ch = (ks * 4 + g) ^ (a & 7);
      bf16x8 pa = *(const bf16x8*)(Pw + a * 128 + ch * 16);
#pragma unroll
      for (int n = 0; n < 8; ++n) {
        const int row = n * 16 + a;
        const int vch = (ks * 4 + g) ^ (row & 7);
        bf16x8 vf = *(const bf16x8*)((const char*)Vlds + row * 128 + vch * 16);
        o[n] = mfma16(pa, vf, o[n]);
      }
    }
    __syncthreads();
  }

  const int b_ = bh >> 4, h = bh & 15;
  __bf16* Og = Ob + (size_t)(b_ * NSEQ + qbase + w * 16 + g * 4) * DIMC + h * HD;
#pragma unroll
  for (int i = 0; i < 4; ++i) {
    const float inv = 1.f / lrow[i];
#pragma unroll
    for (int n = 0; n < 8; ++n)
      Og[(size_t)i * DIMC + n * 16 + a] = (__bf16)(o[n][i] * inv);
  }
}

// ---------------------------------------------------------------------------
extern "C" void kernel_launch(void* const* d_in, const int* in_sizes, int n_in,
                              void* d_out, int out_size, void* d_ws, size_t ws_size,
                              hipStream_t stream) {
  const float* x = (const float*)d_in[0];
  const float* Wq = (const float*)d_in[1];
  const float* bq = (const float*)d_in[2];
  const float* Wk = (const float*)d_in[3];
  const float* bk = (const float*)d_in[4];
  const float* Wv = (const float*)d_in[5];
  const float* bv = (const float*)d_in[6];
  const float* Wo = (const float*)d_in[7];
  const float* bo = (const float*)d_in[8];
  float* out = (float*)d_out;

  char* ws = (char*)d_ws;
  __bf16* xb    = (__bf16*)(ws + 0);          // 16.78 MB (reused as Ob)
  __bf16* Wqkvb = (__bf16*)(ws + 16777216);   // 25.17 MB
  __bf16* Wob   = (__bf16*)(ws + 41943040);   // 8.39 MB
  __bf16* Qb    = (__bf16*)(ws + 50331648);   // 16.78 MB
  __bf16* Kb    = (__bf16*)(ws + 67108864);   // 16.78 MB
  __bf16* Vtb   = (__bf16*)(ws + 83886080);   // 16.78 MB -> total 100.66 MB
  __bf16* Ob    = xb;

  (void)hipFuncSetAttribute((const void*)qkv256,
                            hipFuncAttributeMaxDynamicSharedMemorySize, 131072);

  cast_bf16<<<dim3(2048), 256, 0, stream>>>(x, xb, MROWS * DIMC);
  cast_bf16<<<dim3(1024), 256, 0, stream>>>(Wq, Wqkvb, DIMC * DIMC);
  cast_bf16<<<dim3(1024), 256, 0, stream>>>(Wk, Wqkvb + (size_t)DIMC * DIMC, DIMC * DIMC);
  cast_bf16<<<dim3(1024), 256, 0, stream>>>(Wv, Wqkvb + (size_t)2 * DIMC * DIMC, DIMC * DIMC);
  cast_bf16<<<dim3(1024), 256, 0, stream>>>(Wo, Wob, DIMC * DIMC);

  qkv256<<<dim3(NQKV / 256, MROWS / 256), 512, 131072, stream>>>(
      xb, Wqkvb, Qb, Kb, Vtb, bq, bk, bv);

  attn_swa<<<dim3(NSEQ / 64, BATCH * NH), 256, 0, stream>>>(Qb, Kb, Vtb, Ob);

  gemm_out<<<dim3(DIMC / 128, MROWS / 128), 256, 0, stream>>>(
      Ob, Wob, bo, out);
}

// Round 6
// 293.401 us; speedup vs baseline: 1.0566x; 1.0566x over previous
//
#include <hip/hip_runtime.h>
#include <cstdint>

#define DIMC 2048
#define NSEQ 2048
#define BATCH 2
#define NH 16
#define HD 128
#define MROWS 4096            // BATCH*NSEQ
#define NQKV 6144             // 3*DIMC
#define QSCALE 0.08838834764831845f

typedef float f32x4 __attribute__((ext_vector_type(4)));
typedef __bf16 bf16x8 __attribute__((ext_vector_type(8)));
typedef __bf16 bf16x4 __attribute__((ext_vector_type(4)));

__device__ __forceinline__ f32x4 mfma16(bf16x8 a, bf16x8 b, f32x4 c) {
  return __builtin_amdgcn_mfma_f32_16x16x32_bf16(a, b, c, 0, 0, 0);
}

typedef __attribute__((address_space(1))) void gvoid;
typedef __attribute__((address_space(3))) void ldsvoid;

__device__ __forceinline__ void async16(void* lds, const void* g) {
  __builtin_amdgcn_global_load_lds((gvoid*)(uintptr_t)g, (ldsvoid*)(uintptr_t)lds, 16, 0, 0);
}

#define BAR() asm volatile("s_barrier" ::: "memory")
#define VMCNT0() asm volatile("s_waitcnt vmcnt(0)" ::: "memory")

// ---------------------------------------------------------------------------
// fp32 -> bf16 casts
// ---------------------------------------------------------------------------
__global__ __launch_bounds__(256) void cast_x(const float* __restrict__ src,
                                              __bf16* __restrict__ dst) {
  const int i = (blockIdx.x * 256 + threadIdx.x) * 4;  // grid covers exactly n
  const float4 v = *(const float4*)(src + i);
  bf16x4 o = {(__bf16)v.x, (__bf16)v.y, (__bf16)v.z, (__bf16)v.w};
  *(bf16x4*)(dst + i) = o;
}

__global__ __launch_bounds__(256) void cast_w(const float* __restrict__ Wq,
                                              const float* __restrict__ Wk,
                                              const float* __restrict__ Wv,
                                              const float* __restrict__ Wo,
                                              __bf16* __restrict__ Wqkvb,
                                              __bf16* __restrict__ Wob) {
  const int m = blockIdx.y;
  const float* s = (m == 0) ? Wq : (m == 1) ? Wk : (m == 2) ? Wv : Wo;
  __bf16* d = (m == 3) ? Wob : Wqkvb + (size_t)m * DIMC * DIMC;
  const int i = (blockIdx.x * 256 + threadIdx.x) * 4;  // grid covers exactly DIMC*DIMC
  const float4 v = *(const float4*)(s + i);
  bf16x4 o = {(__bf16)v.x, (__bf16)v.y, (__bf16)v.z, (__bf16)v.w};
  *(bf16x4*)(d + i) = o;
}

// ---------------------------------------------------------------------------
// GEMM  C[M][N] = A[M][K] * B[N][K]^T (+bias), K = 2048, 128x128 tile (m97).
// Reverted to the R2-validated 132us kernel (8-phase 256^2 experiment failed:
// R3-R5 measured 152-162us at 27% MfmaUtil; see journal).
// EPI 0: QKV epilogue; EPI 1: out epilogue (fp32 to d_out).
// ---------------------------------------------------------------------------
template <int EPI>
__global__ __launch_bounds__(256) void gemm_bt(
    const __bf16* __restrict__ A, const __bf16* __restrict__ Bm,
    __bf16* __restrict__ Qb, __bf16* __restrict__ Kb, __bf16* __restrict__ Vtb,
    const float* __restrict__ bias0, const float* __restrict__ bias1,
    const float* __restrict__ bias2, float* __restrict__ outp) {
  __shared__ __bf16 Al[128 * 32];
  __shared__ __bf16 Bl[128 * 32];
  const int tid = threadIdx.x;
  const int w = tid >> 6, l = tid & 63;
  const int a = l & 15, g = l >> 4;
  const int mbase = blockIdx.y * 128, nbase = blockIdx.x * 128;
  const int wr = w >> 1, wc = w & 1;

  f32x4 acc[4][4] = {};

  const char* Ag = (const char*)A +
      ((size_t)(mbase + w * 32 + (l >> 2)) * DIMC + (size_t)(l & 3) * 8) * 2;
  const char* Bg = (const char*)Bm +
      ((size_t)(nbase + w * 32 + (l >> 2)) * DIMC + (size_t)(l & 3) * 8) * 2;
  char* Alw = (char*)Al + w * 2048;
  char* Blw = (char*)Bl + w * 2048;

  for (int kt = 0; kt < DIMC / 32; ++kt) {
    const size_t ko = (size_t)kt * 64;
    async16(Alw, Ag + ko);
    async16(Alw + 1024, Ag + (size_t)16 * (DIMC * 2) + ko);
    async16(Blw, Bg + ko);
    async16(Blw + 1024, Bg + (size_t)16 * (DIMC * 2) + ko);
    __syncthreads();
    bf16x8 af[4], bf_[4];
#pragma unroll
    for (int m = 0; m < 4; ++m)
      af[m] = *(const bf16x8*)((const char*)Al + (wr * 64 + m * 16 + a) * 64 + g * 16);
#pragma unroll
    for (int n = 0; n < 4; ++n)
      bf_[n] = *(const bf16x8*)((const char*)Bl + (wc * 64 + n * 16 + a) * 64 + g * 16);
#pragma unroll
    for (int m = 0; m < 4; ++m)
#pragma unroll
      for (int n = 0; n < 4; ++n) acc[m][n] = mfma16(af[m], bf_[n], acc[m][n]);
    __syncthreads();
  }

  if constexpr (EPI == 0) {
    const int seg = nbase >> 11;               // 0=q 1=k 2=v
    const int cin = (nbase & 2047) + wc * 64;
    const float* bias = (seg == 0) ? bias0 : ((seg == 1) ? bias1 : bias2);
    const float scl = (seg == 0) ? QSCALE : 1.0f;
#pragma unroll
    for (int n = 0; n < 4; ++n) {
      const int c = cin + n * 16 + a;
      const float bb = bias[c];
      const int h = c >> 7, d = c & 127;
#pragma unroll
      for (int m = 0; m < 4; ++m) {
        const int mr = mbase + wr * 64 + m * 16 + g * 4;
        const int b_ = mr >> 11, sq = mr & 2047;
        f32x4 v = acc[m][n];
        if (seg == 2) {
          __bf16* dst = Vtb + ((size_t)(b_ * NH + h) * HD + d) * NSEQ + sq;
          bf16x4 pk = {(__bf16)(v[0] + bb), (__bf16)(v[1] + bb),
                       (__bf16)(v[2] + bb), (__bf16)(v[3] + bb)};
          *(bf16x4*)dst = pk;
        } else {
          __bf16* dst = ((seg == 0) ? Qb : Kb) +
                        ((size_t)(b_ * NH + h) * NSEQ + sq) * HD + d;
#pragma unroll
          for (int j = 0; j < 4; ++j) dst[(size_t)j * HD] = (__bf16)((v[j] + bb) * scl);
        }
      }
    }
  } else {
#pragma unroll
    for (int n = 0; n < 4; ++n) {
      const int c = nbase + wc * 64 + n * 16 + a;
      const float bb = bias0[c];
#pragma unroll
      for (int m = 0; m < 4; ++m) {
        const int mr = mbase + wr * 64 + m * 16 + g * 4;
        float* dst = outp + (size_t)mr * DIMC + c;
        f32x4 v = acc[m][n];
#pragma unroll
        for (int j = 0; j < 4; ++j) dst[(size_t)j * DIMC] = v[j] + bb;
      }
    }
  }
}

// ---------------------------------------------------------------------------
// Sliding-window flash attention v2: QBLK=256 (8 waves x 32 q-rows), KVBLK=64,
// double-buffered KV in dynamic LDS. Grid = (2048/256, 32) = 256 blocks =
// exactly 1/CU. Staging per block <= 20 tiles x 32KB (vs 17 per 64-q block
// before): ~6.7x less aggregate staging traffic.
// LDS 96KB: buf b at b*32768 { K[64][128] 16KB | Vt[128][64] 16KB },
// P at 65536 + w*4096 ([32 q][64 kv] per wave).
// Chunk-XOR swizzle (measured 0 conflicts in R4 family): LDS[row][c] holds
// G[row][c ^ (row&7)]; linear gload_lds dest + pre-swizzled global source.
// ---------------------------------------------------------------------------
__global__ __launch_bounds__(512) void attn_swa2(const __bf16* __restrict__ Qb,
                                                 const __bf16* __restrict__ Kb,
                                                 const __bf16* __restrict__ Vtb,
                                                 __bf16* __restrict__ Ob) {
  extern __shared__ __align__(16) char AL[];
  const int tid = threadIdx.x;
  const int w = tid >> 6, l = tid & 63;
  const int a = l & 15, g = l >> 4;
  const int bh = blockIdx.y;
  const int qbase = blockIdx.x * 256;
  const __bf16* Qg = Qb + (size_t)bh * NSEQ * HD;
  const char* Kg = (const char*)(Kb + (size_t)bh * NSEQ * HD);
  const char* Vg = (const char*)(Vtb + (size_t)bh * HD * NSEQ);

  // Q fragments: 2 q-frags x 4 d-slices (rows w*32 + qi*16 + a)
  bf16x8 qf[2][4];
#pragma unroll
  for (int qi = 0; qi < 2; ++qi)
#pragma unroll
    for (int s = 0; s < 4; ++s)
      qf[qi][s] = *(const bf16x8*)(Qg + (size_t)(qbase + w * 32 + qi * 16 + a) * HD + s * 32 + g * 8);

  float mrow[2][4], lrow[2][4];
#pragma unroll
  for (int qi = 0; qi < 2; ++qi)
#pragma unroll
    for (int i = 0; i < 4; ++i) { mrow[qi][i] = -1e38f; lrow[qi][i] = 0.f; }
  f32x4 o[2][8] = {};

  const int ktlo = (qbase >= 1024) ? ((qbase - 1024) >> 6) : 0;
  const int kthi = (qbase + 255) >> 6;

  auto stage = [&](int b, int kt) {
    const int kb2 = kt * 64;
    char* Kl = AL + b * 32768;
    char* Vl = AL + b * 32768 + 16384;
#pragma unroll
    for (int j = 0; j < 2; ++j) {  // K tile [64 kv][128 d] = 2 x 8KB ops
      const int row = j * 32 + (tid >> 4);
      const int ch = (tid & 15) ^ ((tid >> 4) & 7);
      async16(Kl + j * 8192 + w * 1024, Kg + (size_t)(kb2 + row) * 256 + ch * 16);
    }
#pragma unroll
    for (int j = 0; j < 2; ++j) {  // Vt tile [128 d][64 kv] = 2 x 8KB ops
      const int row = j * 64 + (tid >> 3);
      const int ch = (tid & 7) ^ ((tid >> 3) & 7);
      async16(Vl + j * 8192 + w * 1024,
              Vg + (size_t)row * (NSEQ * 2) + (size_t)kb2 * 2 + ch * 16);
    }
  };

  stage(0, ktlo);
  VMCNT0(); BAR();
  int buf = 0;
  char* Pw = AL + 65536 + w * 4096;

  for (int kt = ktlo; kt <= kthi; ++kt) {
    if (kt < kthi) stage(buf ^ 1, kt + 1);
    const char* Kl = AL + buf * 32768;
    const char* Vl = AL + buf * 32768 + 16384;
    const int kb2 = kt * 64;
    const bool full = (kb2 >= qbase + 255 - 1024) && (kb2 + 63 <= qbase);

    f32x4 s4[2][4];
#pragma unroll
    for (int qi = 0; qi < 2; ++qi)
#pragma unroll
      for (int t = 0; t < 4; ++t) {
        f32x4 sc = {};
#pragma unroll
        for (int ds = 0; ds < 4; ++ds) {
          const int row = t * 16 + a;
          const int ch = (ds * 4 + g) ^ (row & 7);
          bf16x8 kf = *(const bf16x8*)(Kl + row * 256 + ch * 16);
          sc = mfma16(qf[qi][ds], kf, sc);
        }
        s4[qi][t] = sc;
      }

    if (!full) {
#pragma unroll
      for (int qi = 0; qi < 2; ++qi)
#pragma unroll
        for (int t = 0; t < 4; ++t)
#pragma unroll
          for (int i = 0; i < 4; ++i) {
            const int q = qbase + w * 32 + qi * 16 + g * 4 + i;
            const int kv = kb2 + t * 16 + a;
            if (kv > q || kv + 1024 < q) s4[qi][t][i] = -1e30f;
          }
    }

#pragma unroll
    for (int qi = 0; qi < 2; ++qi) {
      float pm[4], corr[4], rs[4];
#pragma unroll
      for (int i = 0; i < 4; ++i)
        pm[i] = fmaxf(fmaxf(s4[qi][0][i], s4[qi][1][i]),
                      fmaxf(s4[qi][2][i], s4[qi][3][i]));
#pragma unroll
      for (int i = 0; i < 4; ++i) {
        pm[i] = fmaxf(pm[i], __shfl_xor(pm[i], 1));
        pm[i] = fmaxf(pm[i], __shfl_xor(pm[i], 2));
        pm[i] = fmaxf(pm[i], __shfl_xor(pm[i], 4));
        pm[i] = fmaxf(pm[i], __shfl_xor(pm[i], 8));
        const float nm = fmaxf(mrow[qi][i], pm[i]);
        corr[i] = __expf(mrow[qi][i] - nm);
        mrow[qi][i] = nm;
        rs[i] = 0.f;
      }
#pragma unroll
      for (int t = 0; t < 4; ++t)
#pragma unroll
        for (int i = 0; i < 4; ++i) {
          const float p = __expf(s4[qi][t][i] - mrow[qi][i]);
          s4[qi][t][i] = p;
          rs[i] += p;
        }
#pragma unroll
      for (int i = 0; i < 4; ++i) {
        rs[i] += __shfl_xor(rs[i], 1);
        rs[i] += __shfl_xor(rs[i], 2);
        rs[i] += __shfl_xor(rs[i], 4);
        rs[i] += __shfl_xor(rs[i], 8);
        lrow[qi][i] = lrow[qi][i] * corr[i] + rs[i];
      }
#pragma unroll
      for (int n = 0; n < 8; ++n)
#pragma unroll
        for (int i = 0; i < 4; ++i) o[qi][n][i] *= corr[i];
      // P -> per-wave LDS (swizzled), bf16
#pragma unroll
      for (int t = 0; t < 4; ++t)
#pragma unroll
        for (int i = 0; i < 4; ++i) {
          const int q8 = qi * 16 + g * 4 + i;
          const int byte = (q8 * 128 + (t * 16 + a) * 2) ^ ((q8 & 7) << 4);
          *(__bf16*)(Pw + byte) = (__bf16)s4[qi][t][i];
        }
    }
    // PV: o[qi][n] += P[qi] x Vt
#pragma unroll
    for (int qi = 0; qi < 2; ++qi)
#pragma unroll
      for (int ks = 0; ks < 2; ++ks) {
        const int pb = ((qi * 16 + a) * 128 + ks * 64 + g * 16) ^ ((a & 7) << 4);
        bf16x8 pa = *(const bf16x8*)(Pw + pb);
#pragma unroll
        for (int n = 0; n < 8; ++n) {
          const int row = n * 16 + a;
          const int vch = (ks * 4 + g) ^ (a & 7);
          bf16x8 vf = *(const bf16x8*)(Vl + row * 128 + vch * 16);
          o[qi][n] = mfma16(pa, vf, o[qi][n]);
        }
      }

    VMCNT0(); BAR();
    buf ^= 1;
  }

  const int b_ = bh >> 4, h = bh & 15;
#pragma unroll
  for (int qi = 0; qi < 2; ++qi) {
    __bf16* Og = Ob + (size_t)(b_ * NSEQ + qbase + w * 32 + qi * 16 + g * 4) * DIMC + h * HD;
#pragma unroll
    for (int i = 0; i < 4; ++i) {
      const float inv = 1.f / lrow[qi][i];
#pragma unroll
      for (int n = 0; n < 8; ++n)
        Og[(size_t)i * DIMC + n * 16 + a] = (__bf16)(o[qi][n][i] * inv);
    }
  }
}

// ---------------------------------------------------------------------------
extern "C" void kernel_launch(void* const* d_in, const int* in_sizes, int n_in,
                              void* d_out, int out_size, void* d_ws, size_t ws_size,
                              hipStream_t stream) {
  const float* x = (const float*)d_in[0];
  const float* Wq = (const float*)d_in[1];
  const float* bq = (const float*)d_in[2];
  const float* Wk = (const float*)d_in[3];
  const float* bk = (const float*)d_in[4];
  const float* Wv = (const float*)d_in[5];
  const float* bv = (const float*)d_in[6];
  const float* Wo = (const float*)d_in[7];
  const float* bo = (const float*)d_in[8];
  float* out = (float*)d_out;

  char* ws = (char*)d_ws;
  __bf16* xb    = (__bf16*)(ws + 0);          // 16.78 MB (reused as Ob)
  __bf16* Wqkvb = (__bf16*)(ws + 16777216);   // 25.17 MB
  __bf16* Wob   = (__bf16*)(ws + 41943040);   // 8.39 MB
  __bf16* Qb    = (__bf16*)(ws + 50331648);   // 16.78 MB
  __bf16* Kb    = (__bf16*)(ws + 67108864);   // 16.78 MB
  __bf16* Vtb   = (__bf16*)(ws + 83886080);   // 16.78 MB -> total 100.66 MB
  __bf16* Ob    = xb;

  (void)hipFuncSetAttribute((const void*)attn_swa2,
                            hipFuncAttributeMaxDynamicSharedMemorySize, 98304);

  cast_x<<<dim3(MROWS * DIMC / 1024), 256, 0, stream>>>(x, xb);
  cast_w<<<dim3(DIMC * DIMC / 1024, 4), 256, 0, stream>>>(Wq, Wk, Wv, Wo, Wqkvb, Wob);

  gemm_bt<0><<<dim3(NQKV / 128, MROWS / 128), 256, 0, stream>>>(
      xb, Wqkvb, Qb, Kb, Vtb, bq, bk, bv, nullptr);

  attn_swa2<<<dim3(NSEQ / 256, BATCH * NH), 512, 98304, stream>>>(Qb, Kb, Vtb, Ob);

  gemm_bt<1><<<dim3(DIMC / 128, MROWS / 128), 256, 0, stream>>>(
      Ob, Wob, nullptr, nullptr, nullptr, bo, nullptr, nullptr, out);
}

// Round 7
// 256.373 us; speedup vs baseline: 1.2092x; 1.1444x over previous
//
#include <hip/hip_runtime.h>
#include <cstdint>

#define DIMC 2048
#define NSEQ 2048
#define BATCH 2
#define NH 16
#define HD 128
#define MROWS 4096            // BATCH*NSEQ
#define NQKV 6144             // 3*DIMC
#define QSCALE 0.08838834764831845f

typedef float f32x4 __attribute__((ext_vector_type(4)));
typedef __bf16 bf16x8 __attribute__((ext_vector_type(8)));
typedef __bf16 bf16x4 __attribute__((ext_vector_type(4)));

__device__ __forceinline__ f32x4 mfma16(bf16x8 a, bf16x8 b, f32x4 c) {
  return __builtin_amdgcn_mfma_f32_16x16x32_bf16(a, b, c, 0, 0, 0);
}

typedef __attribute__((address_space(1))) void gvoid;
typedef __attribute__((address_space(3))) void ldsvoid;

__device__ __forceinline__ void async16(void* lds, const void* g) {
  __builtin_amdgcn_global_load_lds((gvoid*)(uintptr_t)g, (ldsvoid*)(uintptr_t)lds, 16, 0, 0);
}

#define BAR() asm volatile("s_barrier" ::: "memory")
#define VMCNT0() asm volatile("s_waitcnt vmcnt(0)" ::: "memory")

// ---------------------------------------------------------------------------
// fp32 -> bf16 casts
// ---------------------------------------------------------------------------
__global__ __launch_bounds__(256) void cast_x(const float* __restrict__ src,
                                              __bf16* __restrict__ dst) {
  const int i = (blockIdx.x * 256 + threadIdx.x) * 4;
  const float4 v = *(const float4*)(src + i);
  bf16x4 o = {(__bf16)v.x, (__bf16)v.y, (__bf16)v.z, (__bf16)v.w};
  *(bf16x4*)(dst + i) = o;
}

__global__ __launch_bounds__(256) void cast_w(const float* __restrict__ Wq,
                                              const float* __restrict__ Wk,
                                              const float* __restrict__ Wv,
                                              const float* __restrict__ Wo,
                                              __bf16* __restrict__ Wqkvb,
                                              __bf16* __restrict__ Wob) {
  const int m = blockIdx.y;
  const float* s = (m == 0) ? Wq : (m == 1) ? Wk : (m == 2) ? Wv : Wo;
  __bf16* d = (m == 3) ? Wob : Wqkvb + (size_t)m * DIMC * DIMC;
  const int i = (blockIdx.x * 256 + threadIdx.x) * 4;
  const float4 v = *(const float4*)(s + i);
  bf16x4 o = {(__bf16)v.x, (__bf16)v.y, (__bf16)v.z, (__bf16)v.w};
  *(bf16x4*)(d + i) = o;
}

// ---------------------------------------------------------------------------
// GEMM  C[M][N] = A[M][K] * B[N][K]^T (+bias), K = 2048, 128x128 tile (m97).
// EPI 0: QKV epilogue; EPI 1: out epilogue (fp32 to d_out).
// ---------------------------------------------------------------------------
template <int EPI>
__global__ __launch_bounds__(256) void gemm_bt(
    const __bf16* __restrict__ A, const __bf16* __restrict__ Bm,
    __bf16* __restrict__ Qb, __bf16* __restrict__ Kb, __bf16* __restrict__ Vtb,
    const float* __restrict__ bias0, const float* __restrict__ bias1,
    const float* __restrict__ bias2, float* __restrict__ outp) {
  __shared__ __bf16 Al[128 * 32];
  __shared__ __bf16 Bl[128 * 32];
  const int tid = threadIdx.x;
  const int w = tid >> 6, l = tid & 63;
  const int a = l & 15, g = l >> 4;
  const int mbase = blockIdx.y * 128, nbase = blockIdx.x * 128;
  const int wr = w >> 1, wc = w & 1;

  f32x4 acc[4][4] = {};

  const char* Ag = (const char*)A +
      ((size_t)(mbase + w * 32 + (l >> 2)) * DIMC + (size_t)(l & 3) * 8) * 2;
  const char* Bg = (const char*)Bm +
      ((size_t)(nbase + w * 32 + (l >> 2)) * DIMC + (size_t)(l & 3) * 8) * 2;
  char* Alw = (char*)Al + w * 2048;
  char* Blw = (char*)Bl + w * 2048;

  for (int kt = 0; kt < DIMC / 32; ++kt) {
    const size_t ko = (size_t)kt * 64;
    async16(Alw, Ag + ko);
    async16(Alw + 1024, Ag + (size_t)16 * (DIMC * 2) + ko);
    async16(Blw, Bg + ko);
    async16(Blw + 1024, Bg + (size_t)16 * (DIMC * 2) + ko);
    __syncthreads();
    bf16x8 af[4], bf_[4];
#pragma unroll
    for (int m = 0; m < 4; ++m)
      af[m] = *(const bf16x8*)((const char*)Al + (wr * 64 + m * 16 + a) * 64 + g * 16);
#pragma unroll
    for (int n = 0; n < 4; ++n)
      bf_[n] = *(const bf16x8*)((const char*)Bl + (wc * 64 + n * 16 + a) * 64 + g * 16);
#pragma unroll
    for (int m = 0; m < 4; ++m)
#pragma unroll
      for (int n = 0; n < 4; ++n) acc[m][n] = mfma16(af[m], bf_[n], acc[m][n]);
    __syncthreads();
  }

  if constexpr (EPI == 0) {
    const int seg = nbase >> 11;               // 0=q 1=k 2=v
    const int cin = (nbase & 2047) + wc * 64;
    const float* bias = (seg == 0) ? bias0 : ((seg == 1) ? bias1 : bias2);
    const float scl = (seg == 0) ? QSCALE : 1.0f;
#pragma unroll
    for (int n = 0; n < 4; ++n) {
      const int c = cin + n * 16 + a;
      const float bb = bias[c];
      const int h = c >> 7, d = c & 127;
#pragma unroll
      for (int m = 0; m < 4; ++m) {
        const int mr = mbase + wr * 64 + m * 16 + g * 4;
        const int b_ = mr >> 11, sq = mr & 2047;
        f32x4 v = acc[m][n];
        if (seg == 2) {
          __bf16* dst = Vtb + ((size_t)(b_ * NH + h) * HD + d) * NSEQ + sq;
          bf16x4 pk = {(__bf16)(v[0] + bb), (__bf16)(v[1] + bb),
                       (__bf16)(v[2] + bb), (__bf16)(v[3] + bb)};
          *(bf16x4*)dst = pk;
        } else {
          __bf16* dst = ((seg == 0) ? Qb : Kb) +
                        ((size_t)(b_ * NH + h) * NSEQ + sq) * HD + d;
#pragma unroll
          for (int j = 0; j < 4; ++j) dst[(size_t)j * HD] = (__bf16)((v[j] + bb) * scl);
        }
      }
    }
  } else {
#pragma unroll
    for (int n = 0; n < 4; ++n) {
      const int c = nbase + wc * 64 + n * 16 + a;
      const float bb = bias0[c];
#pragma unroll
      for (int m = 0; m < 4; ++m) {
        const int mr = mbase + wr * 64 + m * 16 + g * 4;
        float* dst = outp + (size_t)mr * DIMC + c;
        f32x4 v = acc[m][n];
#pragma unroll
        for (int j = 0; j < 4; ++j) dst[(size_t)j * DIMC] = v[j] + bb;
      }
    }
  }
}

// ---------------------------------------------------------------------------
// Sliding-window flash attention v3: swapped-operand (S^T / O^T) structure.
// QBLK=256 (8 waves x 32 q), KVBLK=64, double-buffered KV in 96KB dyn LDS.
// QK^T computed as mfma(K,Q) -> S^T[kv][q]: lane holds 16 S-values for ONE
// q-row (q = lane&15) -> softmax reduce = 15 in-lane fmax + 2 shfl (was 16).
// PV computed as mfma(V^T, P^T) -> O^T[d][q]: softmax state and accumulator
// live in the same lane; K/V fragments hoisted (read once, used for both qi).
// T13 defer-max (THR=8) skips the O-rescale when the running max holds.
// LDS-pipe ops/tile/wave: ~76 vs v2's ~148 (theory: attn is LDS-pipe-bound).
// ---------------------------------------------------------------------------
__global__ __launch_bounds__(512) void attn_swa3(const __bf16* __restrict__ Qb,
                                                 const __bf16* __restrict__ Kb,
                                                 const __bf16* __restrict__ Vtb,
                                                 __bf16* __restrict__ Ob) {
  extern __shared__ __align__(16) char AL[];
  const int tid = threadIdx.x;
  const int w = tid >> 6, l = tid & 63;
  const int a = l & 15, g = l >> 4;
  const int bh = blockIdx.y;
  const int qbase = blockIdx.x * 256;
  const __bf16* Qg = Qb + (size_t)bh * NSEQ * HD;
  const char* Kg = (const char*)(Kb + (size_t)bh * NSEQ * HD);
  const char* Vg = (const char*)(Vtb + (size_t)bh * HD * NSEQ);

  // Q fragments (row = this lane's q within the wave's 32 rows)
  bf16x8 qf[2][4];
#pragma unroll
  for (int qi = 0; qi < 2; ++qi)
#pragma unroll
    for (int s = 0; s < 4; ++s)
      qf[qi][s] = *(const bf16x8*)(Qg + (size_t)(qbase + w * 32 + qi * 16 + a) * HD + s * 32 + g * 8);

  float mrow[2] = {-1e38f, -1e38f}, lrow[2] = {0.f, 0.f};
  f32x4 o[2][8] = {};   // O^T: o[qi][n][reg] = O[d = n*16+g*4+reg][q = qi*16+a]

  const int ktlo = (qbase >= 1024) ? ((qbase - 1024) >> 6) : 0;
  const int kthi = (qbase + 255) >> 6;

  auto stage = [&](int b, int kt) {
    const int kb2 = kt * 64;
    char* Kl = AL + b * 32768;
    char* Vl = AL + b * 32768 + 16384;
#pragma unroll
    for (int j = 0; j < 2; ++j) {  // K tile [64 kv][128 d]
      const int row = j * 32 + (tid >> 4);
      const int ch = (tid & 15) ^ ((tid >> 4) & 7);
      async16(Kl + j * 8192 + w * 1024, Kg + (size_t)(kb2 + row) * 256 + ch * 16);
    }
#pragma unroll
    for (int j = 0; j < 2; ++j) {  // Vt tile [128 d][64 kv]
      const int row = j * 64 + (tid >> 3);
      const int ch = (tid & 7) ^ ((tid >> 3) & 7);
      async16(Vl + j * 8192 + w * 1024,
              Vg + (size_t)row * (NSEQ * 2) + (size_t)kb2 * 2 + ch * 16);
    }
  };

  stage(0, ktlo);
  VMCNT0(); BAR();
  int buf = 0;
  char* Pw = AL + 65536 + w * 4096;   // per-wave P[32 q][64 kv] bf16, swizzled

  for (int kt = ktlo; kt <= kthi; ++kt) {
    if (kt < kthi) stage(buf ^ 1, kt + 1);
    const char* Kl = AL + buf * 32768;
    const char* Vl = AL + buf * 32768 + 16384;
    const int kb2 = kt * 64;
    const bool full = (kb2 >= qbase + 255 - 1024) && (kb2 + 63 <= qbase);

    // S^T = K x Q^T : s4[qi][t][i] = S[kv = kb2+t*16+g*4+i][q = qi*16+a]
    f32x4 s4[2][4];
#pragma unroll
    for (int t = 0; t < 4; ++t) {
      bf16x8 kf[4];
#pragma unroll
      for (int ds = 0; ds < 4; ++ds)
        kf[ds] = *(const bf16x8*)(Kl + (t * 16 + a) * 256 + (((ds * 4 + g) ^ (a & 7)) * 16));
#pragma unroll
      for (int qi = 0; qi < 2; ++qi) {
        f32x4 sc = {};
#pragma unroll
        for (int ds = 0; ds < 4; ++ds) sc = mfma16(kf[ds], qf[qi][ds], sc);
        s4[qi][t] = sc;
      }
    }

    if (!full) {
#pragma unroll
      for (int qi = 0; qi < 2; ++qi) {
        const int q = qbase + w * 32 + qi * 16 + a;
#pragma unroll
        for (int t = 0; t < 4; ++t)
#pragma unroll
          for (int i = 0; i < 4; ++i) {
            const int kv = kb2 + t * 16 + g * 4 + i;
            if (kv > q || kv + 1024 < q) s4[qi][t][i] = -1e30f;
          }
      }
    }

#pragma unroll
    for (int qi = 0; qi < 2; ++qi) {
      float pm = s4[qi][0][0];
#pragma unroll
      for (int t = 0; t < 4; ++t)
#pragma unroll
        for (int i = 0; i < 4; ++i)
          if (t || i) pm = fmaxf(pm, s4[qi][t][i]);
      pm = fmaxf(pm, __shfl_xor(pm, 16));
      pm = fmaxf(pm, __shfl_xor(pm, 32));
      if (!__all(pm - mrow[qi] <= 8.f)) {   // T13 defer-max
        const float nm = fmaxf(mrow[qi], pm);
        const float corr = __expf(mrow[qi] - nm);
        mrow[qi] = nm;
        lrow[qi] *= corr;
#pragma unroll
        for (int n = 0; n < 8; ++n)
#pragma unroll
          for (int i = 0; i < 4; ++i) o[qi][n][i] *= corr;
      }
      float rs = 0.f;
#pragma unroll
      for (int t = 0; t < 4; ++t)
#pragma unroll
        for (int i = 0; i < 4; ++i) {
          const float p = __expf(s4[qi][t][i] - mrow[qi]);
          s4[qi][t][i] = p;
          rs += p;
        }
      rs += __shfl_xor(rs, 16);
      rs += __shfl_xor(rs, 32);
      lrow[qi] += rs;
      // P[q][kv] -> per-wave LDS (chunk-XOR swizzled by q&7 = a&7)
      const int prow = qi * 16 + a;
#pragma unroll
      for (int t = 0; t < 4; ++t)
#pragma unroll
        for (int i = 0; i < 4; ++i) {
          const int byte = (prow * 128 + (t * 16 + g * 4 + i) * 2) ^ ((a & 7) << 4);
          *(__bf16*)(Pw + byte) = (__bf16)s4[qi][t][i];
        }
    }

    // O^T += V^T x P^T (A = Vt frag, B = P frag; V read once per (ks,n))
#pragma unroll
    for (int ks = 0; ks < 2; ++ks) {
      bf16x8 pa[2];
#pragma unroll
      for (int qi = 0; qi < 2; ++qi)
        pa[qi] = *(const bf16x8*)(Pw + (((qi * 16 + a) * 128 + ks * 64 + g * 16) ^ ((a & 7) << 4)));
#pragma unroll
      for (int n = 0; n < 8; ++n) {
        bf16x8 va = *(const bf16x8*)(Vl + (n * 16 + a) * 128 + (((ks * 4 + g) ^ (a & 7)) * 16));
#pragma unroll
        for (int qi = 0; qi < 2; ++qi) o[qi][n] = mfma16(va, pa[qi], o[qi][n]);
      }
    }

    VMCNT0(); BAR();
    buf ^= 1;
  }

  const int b_ = bh >> 4, h = bh & 15;
#pragma unroll
  for (int qi = 0; qi < 2; ++qi) {
    const int q = qbase + w * 32 + qi * 16 + a;
    const float inv = 1.f / lrow[qi];
    __bf16* Og = Ob + (size_t)(b_ * NSEQ + q) * DIMC + h * HD + g * 4;
#pragma unroll
    for (int n = 0; n < 8; ++n) {
      bf16x4 pk = {(__bf16)(o[qi][n][0] * inv), (__bf16)(o[qi][n][1] * inv),
                   (__bf16)(o[qi][n][2] * inv), (__bf16)(o[qi][n][3] * inv)};
      *(bf16x4*)(Og + (size_t)n * 16) = pk;
    }
  }
}

// ---------------------------------------------------------------------------
extern "C" void kernel_launch(void* const* d_in, const int* in_sizes, int n_in,
                              void* d_out, int out_size, void* d_ws, size_t ws_size,
                              hipStream_t stream) {
  const float* x = (const float*)d_in[0];
  const float* Wq = (const float*)d_in[1];
  const float* bq = (const float*)d_in[2];
  const float* Wk = (const float*)d_in[3];
  const float* bk = (const float*)d_in[4];
  const float* Wv = (const float*)d_in[5];
  const float* bv = (const float*)d_in[6];
  const float* Wo = (const float*)d_in[7];
  const float* bo = (const float*)d_in[8];
  float* out = (float*)d_out;

  char* ws = (char*)d_ws;
  __bf16* xb    = (__bf16*)(ws + 0);          // 16.78 MB (reused as Ob)
  __bf16* Wqkvb = (__bf16*)(ws + 16777216);   // 25.17 MB
  __bf16* Wob   = (__bf16*)(ws + 41943040);   // 8.39 MB
  __bf16* Qb    = (__bf16*)(ws + 50331648);   // 16.78 MB
  __bf16* Kb    = (__bf16*)(ws + 67108864);   // 16.78 MB
  __bf16* Vtb   = (__bf16*)(ws + 83886080);   // 16.78 MB -> total 100.66 MB
  __bf16* Ob    = xb;

  (void)hipFuncSetAttribute((const void*)attn_swa3,
                            hipFuncAttributeMaxDynamicSharedMemorySize, 98304);

  cast_x<<<dim3(MROWS * DIMC / 1024), 256, 0, stream>>>(x, xb);
  cast_w<<<dim3(DIMC * DIMC / 1024, 4), 256, 0, stream>>>(Wq, Wk, Wv, Wo, Wqkvb, Wob);

  gemm_bt<0><<<dim3(NQKV / 128, MROWS / 128), 256, 0, stream>>>(
      xb, Wqkvb, Qb, Kb, Vtb, bq, bk, bv, nullptr);

  attn_swa3<<<dim3(NSEQ / 256, BATCH * NH), 512, 98304, stream>>>(Qb, Kb, Vtb, Ob);

  gemm_bt<1><<<dim3(DIMC / 128, MROWS / 128), 256, 0, stream>>>(
      Ob, Wob, nullptr, nullptr, nullptr, bo, nullptr, nullptr, out);
}

// Round 8
// 254.809 us; speedup vs baseline: 1.2166x; 1.0061x over previous
//
#include <hip/hip_runtime.h>
#include <cstdint>

#define DIMC 2048
#define NSEQ 2048
#define BATCH 2
#define NH 16
#define HD 128
#define MROWS 4096            // BATCH*NSEQ
#define NQKV 6144             // 3*DIMC
#define QSCALE 0.08838834764831845f

typedef float f32x4 __attribute__((ext_vector_type(4)));
typedef __bf16 bf16x8 __attribute__((ext_vector_type(8)));
typedef __bf16 bf16x4 __attribute__((ext_vector_type(4)));

__device__ __forceinline__ f32x4 mfma16(bf16x8 a, bf16x8 b, f32x4 c) {
  return __builtin_amdgcn_mfma_f32_16x16x32_bf16(a, b, c, 0, 0, 0);
}

typedef __attribute__((address_space(1))) void gvoid;
typedef __attribute__((address_space(3))) void ldsvoid;

__device__ __forceinline__ void async16(void* lds, const void* g) {
  __builtin_amdgcn_global_load_lds((gvoid*)(uintptr_t)g, (ldsvoid*)(uintptr_t)lds, 16, 0, 0);
}

#define BAR() asm volatile("s_barrier" ::: "memory")
#define VMCNT0() asm volatile("s_waitcnt vmcnt(0)" ::: "memory")

// ---------------------------------------------------------------------------
// fp32 -> bf16 casts
// ---------------------------------------------------------------------------
__global__ __launch_bounds__(256) void cast_x(const float* __restrict__ src,
                                              __bf16* __restrict__ dst) {
  const int i = (blockIdx.x * 256 + threadIdx.x) * 4;
  const float4 v = *(const float4*)(src + i);
  bf16x4 o = {(__bf16)v.x, (__bf16)v.y, (__bf16)v.z, (__bf16)v.w};
  *(bf16x4*)(dst + i) = o;
}

__global__ __launch_bounds__(256) void cast_w(const float* __restrict__ Wq,
                                              const float* __restrict__ Wk,
                                              const float* __restrict__ Wv,
                                              const float* __restrict__ Wo,
                                              __bf16* __restrict__ Wqkvb,
                                              __bf16* __restrict__ Wob) {
  const int m = blockIdx.y;
  const float* s = (m == 0) ? Wq : (m == 1) ? Wk : (m == 2) ? Wv : Wo;
  __bf16* d = (m == 3) ? Wob : Wqkvb + (size_t)m * DIMC * DIMC;
  const int i = (blockIdx.x * 256 + threadIdx.x) * 4;
  const float4 v = *(const float4*)(s + i);
  bf16x4 o = {(__bf16)v.x, (__bf16)v.y, (__bf16)v.z, (__bf16)v.w};
  *(bf16x4*)(d + i) = o;
}

// ---------------------------------------------------------------------------
// GEMM  C[M][N] = A[M][K] * B[N][K]^T (+bias), K = 2048, 128x128 tile (m97).
// EPI 0: QKV epilogue; EPI 1: out epilogue (fp32 to d_out).
// ---------------------------------------------------------------------------
template <int EPI>
__global__ __launch_bounds__(256) void gemm_bt(
    const __bf16* __restrict__ A, const __bf16* __restrict__ Bm,
    __bf16* __restrict__ Qb, __bf16* __restrict__ Kb, __bf16* __restrict__ Vtb,
    const float* __restrict__ bias0, const float* __restrict__ bias1,
    const float* __restrict__ bias2, float* __restrict__ outp) {
  __shared__ __bf16 Al[128 * 32];
  __shared__ __bf16 Bl[128 * 32];
  const int tid = threadIdx.x;
  const int w = tid >> 6, l = tid & 63;
  const int a = l & 15, g = l >> 4;
  const int mbase = blockIdx.y * 128, nbase = blockIdx.x * 128;
  const int wr = w >> 1, wc = w & 1;

  f32x4 acc[4][4] = {};

  const char* Ag = (const char*)A +
      ((size_t)(mbase + w * 32 + (l >> 2)) * DIMC + (size_t)(l & 3) * 8) * 2;
  const char* Bg = (const char*)Bm +
      ((size_t)(nbase + w * 32 + (l >> 2)) * DIMC + (size_t)(l & 3) * 8) * 2;
  char* Alw = (char*)Al + w * 2048;
  char* Blw = (char*)Bl + w * 2048;

  for (int kt = 0; kt < DIMC / 32; ++kt) {
    const size_t ko = (size_t)kt * 64;
    async16(Alw, Ag + ko);
    async16(Alw + 1024, Ag + (size_t)16 * (DIMC * 2) + ko);
    async16(Blw, Bg + ko);
    async16(Blw + 1024, Bg + (size_t)16 * (DIMC * 2) + ko);
    __syncthreads();
    bf16x8 af[4], bf_[4];
#pragma unroll
    for (int m = 0; m < 4; ++m)
      af[m] = *(const bf16x8*)((const char*)Al + (wr * 64 + m * 16 + a) * 64 + g * 16);
#pragma unroll
    for (int n = 0; n < 4; ++n)
      bf_[n] = *(const bf16x8*)((const char*)Bl + (wc * 64 + n * 16 + a) * 64 + g * 16);
#pragma unroll
    for (int m = 0; m < 4; ++m)
#pragma unroll
      for (int n = 0; n < 4; ++n) acc[m][n] = mfma16(af[m], bf_[n], acc[m][n]);
    __syncthreads();
  }

  if constexpr (EPI == 0) {
    const int seg = nbase >> 11;               // 0=q 1=k 2=v
    const int cin = (nbase & 2047) + wc * 64;
    const float* bias = (seg == 0) ? bias0 : ((seg == 1) ? bias1 : bias2);
    const float scl = (seg == 0) ? QSCALE : 1.0f;
#pragma unroll
    for (int n = 0; n < 4; ++n) {
      const int c = cin + n * 16 + a;
      const float bb = bias[c];
      const int h = c >> 7, d = c & 127;
#pragma unroll
      for (int m = 0; m < 4; ++m) {
        const int mr = mbase + wr * 64 + m * 16 + g * 4;
        const int b_ = mr >> 11, sq = mr & 2047;
        f32x4 v = acc[m][n];
        if (seg == 2) {
          __bf16* dst = Vtb + ((size_t)(b_ * NH + h) * HD + d) * NSEQ + sq;
          bf16x4 pk = {(__bf16)(v[0] + bb), (__bf16)(v[1] + bb),
                       (__bf16)(v[2] + bb), (__bf16)(v[3] + bb)};
          *(bf16x4*)dst = pk;
        } else {
          __bf16* dst = ((seg == 0) ? Qb : Kb) +
                        ((size_t)(b_ * NH + h) * NSEQ + sq) * HD + d;
#pragma unroll
          for (int j = 0; j < 4; ++j) dst[(size_t)j * HD] = (__bf16)((v[j] + bb) * scl);
        }
      }
    }
  } else {
#pragma unroll
    for (int n = 0; n < 4; ++n) {
      const int c = nbase + wc * 64 + n * 16 + a;
      const float bb = bias0[c];
#pragma unroll
      for (int m = 0; m < 4; ++m) {
        const int mr = mbase + wr * 64 + m * 16 + g * 4;
        float* dst = outp + (size_t)mr * DIMC + c;
        f32x4 v = acc[m][n];
#pragma unroll
        for (int j = 0; j < 4; ++j) dst[(size_t)j * DIMC] = v[j] + bb;
      }
    }
  }
}

// ---------------------------------------------------------------------------
// Sliding-window flash attention v4: swapped-operand (S^T / O^T) structure
// (validated R7: 293->256us), plus:
//  - packed P-writes: 8 x ds_write_b64 per wave-tile (was 32 x ds_write_b16);
//    8B block sits below the XOR bits (4-6) so the swizzle is uniform on it;
//    bank map: 2-way aliasing only (a vs a+8) = free (m136).
//  - T5 s_setprio(1) around QK and PV MFMA clusters (attn-positive, m191).
// ---------------------------------------------------------------------------
__global__ __launch_bounds__(512) void attn_swa4(const __bf16* __restrict__ Qb,
                                                 const __bf16* __restrict__ Kb,
                                                 const __bf16* __restrict__ Vtb,
                                                 __bf16* __restrict__ Ob) {
  extern __shared__ __align__(16) char AL[];
  const int tid = threadIdx.x;
  const int w = tid >> 6, l = tid & 63;
  const int a = l & 15, g = l >> 4;
  const int bh = blockIdx.y;
  const int qbase = blockIdx.x * 256;
  const __bf16* Qg = Qb + (size_t)bh * NSEQ * HD;
  const char* Kg = (const char*)(Kb + (size_t)bh * NSEQ * HD);
  const char* Vg = (const char*)(Vtb + (size_t)bh * HD * NSEQ);

  bf16x8 qf[2][4];
#pragma unroll
  for (int qi = 0; qi < 2; ++qi)
#pragma unroll
    for (int s = 0; s < 4; ++s)
      qf[qi][s] = *(const bf16x8*)(Qg + (size_t)(qbase + w * 32 + qi * 16 + a) * HD + s * 32 + g * 8);

  float mrow[2] = {-1e38f, -1e38f}, lrow[2] = {0.f, 0.f};
  f32x4 o[2][8] = {};   // O^T: o[qi][n][reg] = O[d = n*16+g*4+reg][q = qi*16+a]

  const int ktlo = (qbase >= 1024) ? ((qbase - 1024) >> 6) : 0;
  const int kthi = (qbase + 255) >> 6;

  auto stage = [&](int b, int kt) {
    const int kb2 = kt * 64;
    char* Kl = AL + b * 32768;
    char* Vl = AL + b * 32768 + 16384;
#pragma unroll
    for (int j = 0; j < 2; ++j) {  // K tile [64 kv][128 d]
      const int row = j * 32 + (tid >> 4);
      const int ch = (tid & 15) ^ ((tid >> 4) & 7);
      async16(Kl + j * 8192 + w * 1024, Kg + (size_t)(kb2 + row) * 256 + ch * 16);
    }
#pragma unroll
    for (int j = 0; j < 2; ++j) {  // Vt tile [128 d][64 kv]
      const int row = j * 64 + (tid >> 3);
      const int ch = (tid & 7) ^ ((tid >> 3) & 7);
      async16(Vl + j * 8192 + w * 1024,
              Vg + (size_t)row * (NSEQ * 2) + (size_t)kb2 * 2 + ch * 16);
    }
  };

  stage(0, ktlo);
  VMCNT0(); BAR();
  int buf = 0;
  char* Pw = AL + 65536 + w * 4096;   // per-wave P[32 q][64 kv] bf16, swizzled

  for (int kt = ktlo; kt <= kthi; ++kt) {
    if (kt < kthi) stage(buf ^ 1, kt + 1);
    const char* Kl = AL + buf * 32768;
    const char* Vl = AL + buf * 32768 + 16384;
    const int kb2 = kt * 64;
    const bool full = (kb2 >= qbase + 255 - 1024) && (kb2 + 63 <= qbase);

    // S^T = K x Q^T : s4[qi][t][i] = S[kv = kb2+t*16+g*4+i][q = qi*16+a]
    f32x4 s4[2][4];
#pragma unroll
    for (int t = 0; t < 4; ++t) {
      bf16x8 kf[4];
#pragma unroll
      for (int ds = 0; ds < 4; ++ds)
        kf[ds] = *(const bf16x8*)(Kl + (t * 16 + a) * 256 + (((ds * 4 + g) ^ (a & 7)) * 16));
      __builtin_amdgcn_s_setprio(1);
#pragma unroll
      for (int qi = 0; qi < 2; ++qi) {
        f32x4 sc = {};
#pragma unroll
        for (int ds = 0; ds < 4; ++ds) sc = mfma16(kf[ds], qf[qi][ds], sc);
        s4[qi][t] = sc;
      }
      __builtin_amdgcn_s_setprio(0);
    }

    if (!full) {
#pragma unroll
      for (int qi = 0; qi < 2; ++qi) {
        const int q = qbase + w * 32 + qi * 16 + a;
#pragma unroll
        for (int t = 0; t < 4; ++t)
#pragma unroll
          for (int i = 0; i < 4; ++i) {
            const int kv = kb2 + t * 16 + g * 4 + i;
            if (kv > q || kv + 1024 < q) s4[qi][t][i] = -1e30f;
          }
      }
    }

#pragma unroll
    for (int qi = 0; qi < 2; ++qi) {
      float pm = s4[qi][0][0];
#pragma unroll
      for (int t = 0; t < 4; ++t)
#pragma unroll
        for (int i = 0; i < 4; ++i)
          if (t || i) pm = fmaxf(pm, s4[qi][t][i]);
      pm = fmaxf(pm, __shfl_xor(pm, 16));
      pm = fmaxf(pm, __shfl_xor(pm, 32));
      if (!__all(pm - mrow[qi] <= 8.f)) {   // T13 defer-max
        const float nm = fmaxf(mrow[qi], pm);
        const float corr = __expf(mrow[qi] - nm);
        mrow[qi] = nm;
        lrow[qi] *= corr;
#pragma unroll
        for (int n = 0; n < 8; ++n)
#pragma unroll
          for (int i = 0; i < 4; ++i) o[qi][n][i] *= corr;
      }
      float rs = 0.f;
#pragma unroll
      for (int t = 0; t < 4; ++t)
#pragma unroll
        for (int i = 0; i < 4; ++i) {
          const float p = __expf(s4[qi][t][i] - mrow[qi]);
          s4[qi][t][i] = p;
          rs += p;
        }
      rs += __shfl_xor(rs, 16);
      rs += __shfl_xor(rs, 32);
      lrow[qi] += rs;
      // P[q][kv] -> per-wave LDS: 4 packed 8B stores (4 consecutive kv each);
      // XOR swizzle hits bits 4-6 only -> uniform over the 8B block.
      const int prow = qi * 16 + a;
#pragma unroll
      for (int t = 0; t < 4; ++t) {
        bf16x4 pk = {(__bf16)s4[qi][t][0], (__bf16)s4[qi][t][1],
                     (__bf16)s4[qi][t][2], (__bf16)s4[qi][t][3]};
        const int byte = (prow * 128 + (t * 16 + g * 4) * 2) ^ ((a & 7) << 4);
        *(bf16x4*)(Pw + byte) = pk;
      }
    }

    // O^T += V^T x P^T (A = Vt frag, B = P frag; V read once per (ks,n))
#pragma unroll
    for (int ks = 0; ks < 2; ++ks) {
      bf16x8 pa[2];
#pragma unroll
      for (int qi = 0; qi < 2; ++qi)
        pa[qi] = *(const bf16x8*)(Pw + (((qi * 16 + a) * 128 + ks * 64 + g * 16) ^ ((a & 7) << 4)));
#pragma unroll
      for (int n = 0; n < 8; ++n) {
        bf16x8 va = *(const bf16x8*)(Vl + (n * 16 + a) * 128 + (((ks * 4 + g) ^ (a & 7)) * 16));
        __builtin_amdgcn_s_setprio(1);
#pragma unroll
        for (int qi = 0; qi < 2; ++qi) o[qi][n] = mfma16(va, pa[qi], o[qi][n]);
        __builtin_amdgcn_s_setprio(0);
      }
    }

    VMCNT0(); BAR();
    buf ^= 1;
  }

  const int b_ = bh >> 4, h = bh & 15;
#pragma unroll
  for (int qi = 0; qi < 2; ++qi) {
    const int q = qbase + w * 32 + qi * 16 + a;
    const float inv = 1.f / lrow[qi];
    __bf16* Og = Ob + (size_t)(b_ * NSEQ + q) * DIMC + h * HD + g * 4;
#pragma unroll
    for (int n = 0; n < 8; ++n) {
      bf16x4 pk = {(__bf16)(o[qi][n][0] * inv), (__bf16)(o[qi][n][1] * inv),
                   (__bf16)(o[qi][n][2] * inv), (__bf16)(o[qi][n][3] * inv)};
      *(bf16x4*)(Og + (size_t)n * 16) = pk;
    }
  }
}

// ---------------------------------------------------------------------------
extern "C" void kernel_launch(void* const* d_in, const int* in_sizes, int n_in,
                              void* d_out, int out_size, void* d_ws, size_t ws_size,
                              hipStream_t stream) {
  const float* x = (const float*)d_in[0];
  const float* Wq = (const float*)d_in[1];
  const float* bq = (const float*)d_in[2];
  const float* Wk = (const float*)d_in[3];
  const float* bk = (const float*)d_in[4];
  const float* Wv = (const float*)d_in[5];
  const float* bv = (const float*)d_in[6];
  const float* Wo = (const float*)d_in[7];
  const float* bo = (const float*)d_in[8];
  float* out = (float*)d_out;

  char* ws = (char*)d_ws;
  __bf16* xb    = (__bf16*)(ws + 0);          // 16.78 MB (reused as Ob)
  __bf16* Wqkvb = (__bf16*)(ws + 16777216);   // 25.17 MB
  __bf16* Wob   = (__bf16*)(ws + 41943040);   // 8.39 MB
  __bf16* Qb    = (__bf16*)(ws + 50331648);   // 16.78 MB
  __bf16* Kb    = (__bf16*)(ws + 67108864);   // 16.78 MB
  __bf16* Vtb   = (__bf16*)(ws + 83886080);   // 16.78 MB -> total 100.66 MB
  __bf16* Ob    = xb;

  (void)hipFuncSetAttribute((const void*)attn_swa4,
                            hipFuncAttributeMaxDynamicSharedMemorySize, 98304);

  cast_x<<<dim3(MROWS * DIMC / 1024), 256, 0, stream>>>(x, xb);
  cast_w<<<dim3(DIMC * DIMC / 1024, 4), 256, 0, stream>>>(Wq, Wk, Wv, Wo, Wqkvb, Wob);

  gemm_bt<0><<<dim3(NQKV / 128, MROWS / 128), 256, 0, stream>>>(
      xb, Wqkvb, Qb, Kb, Vtb, bq, bk, bv, nullptr);

  attn_swa4<<<dim3(NSEQ / 256, BATCH * NH), 512, 98304, stream>>>(Qb, Kb, Vtb, Ob);

  gemm_bt<1><<<dim3(DIMC / 128, MROWS / 128), 256, 0, stream>>>(
      Ob, Wob, nullptr, nullptr, nullptr, bo, nullptr, nullptr, out);
}